// Round 1
// baseline (205.814 us; speedup 1.0000x reference)
//
#include <hip/hip_runtime.h>
#include <hip/hip_bf16.h>

typedef __attribute__((ext_vector_type(8))) short bf16x8;
typedef __attribute__((ext_vector_type(4))) float f32x4;
typedef __attribute__((ext_vector_type(4))) unsigned short ushort4v;

__device__ __forceinline__ unsigned short f2bf(float f) {
  union { float f; unsigned u; } v; v.f = f;
  unsigned r = v.u + 0x7FFFu + ((v.u >> 16) & 1u);
  return (unsigned short)(r >> 16);
}

__device__ __forceinline__ void gll16(const void* g, void* l) {
  __builtin_amdgcn_global_load_lds((const __attribute__((address_space(1))) void*)g,
                                   (__attribute__((address_space(3))) void*)l, 16, 0, 0);
}

#define MFMA16(a, b, c) __builtin_amdgcn_mfma_f32_16x16x32_bf16((a), (b), (c), 0, 0, 0)

// ---------------------------------------------------------------- convert
__global__ void cvt_f32_bf16(const float* __restrict__ s, unsigned short* __restrict__ d, int n) {
  int i = (blockIdx.x * blockDim.x + threadIdx.x) * 4;
  if (i >= n) return;
  float4 f = *(const float4*)(s + i);
  ushort4v r;
  r[0] = f2bf(f.x); r[1] = f2bf(f.y); r[2] = f2bf(f.z); r[3] = f2bf(f.w);
  *(ushort4v*)(d + i) = r;
}

// ---------------------------------------------------------------- GEMM NT (A[M][K] @ B[N][K]^T)
// EPI 0: scatter bf16 into qkv [3][B,H,T,D];  EPI 1: fp32 out [M][N]
template<int EPI>
__global__ __launch_bounds__(256, 2)
void gemm_nt(const unsigned short* __restrict__ A,
             const unsigned short* __restrict__ B,
             unsigned short* __restrict__ obf,
             float* __restrict__ of32,
             int M, int N, int K) {
  __shared__ unsigned short At[128 * 64];
  __shared__ unsigned short Bt[128 * 64];
  const int tid = threadIdx.x, wid = tid >> 6, lane = tid & 63;
  const int c = lane & 15, g = lane >> 4;
  const int wr = wid >> 1, wc = wid & 1;
  const int m0 = blockIdx.x * 128, n0 = blockIdx.y * 128;

  f32x4 acc[4][4];
#pragma unroll
  for (int i = 0; i < 4; ++i)
#pragma unroll
    for (int j = 0; j < 4; ++j) acc[i][j] = f32x4{0.f, 0.f, 0.f, 0.f};

  for (int kt = 0; kt < K; kt += 64) {
    if (kt) __syncthreads();
#pragma unroll
    for (int r = 0; r < 4; ++r) {
      int chunk = wid * 4 + r;               // 16 chunks of 1024B per tile
      int row = chunk * 8 + (lane >> 3);
      int col = (lane & 7) * 8;
      gll16(A + (size_t)(m0 + row) * K + kt + col, At + chunk * 512);
      gll16(B + (size_t)(n0 + row) * K + kt + col, Bt + chunk * 512);
    }
    __syncthreads();
#pragma unroll
    for (int kk = 0; kk < 2; ++kk) {
      bf16x8 af[4], bfr[4];
#pragma unroll
      for (int i = 0; i < 4; ++i) {
        af[i]  = *(const bf16x8*)(At + (wr * 64 + i * 16 + c) * 64 + kk * 32 + g * 8);
        bfr[i] = *(const bf16x8*)(Bt + (wc * 64 + i * 16 + c) * 64 + kk * 32 + g * 8);
      }
#pragma unroll
      for (int mi = 0; mi < 4; ++mi)
#pragma unroll
        for (int ni = 0; ni < 4; ++ni)
          acc[mi][ni] = MFMA16(af[mi], bfr[ni], acc[mi][ni]);
    }
  }

#pragma unroll
  for (int mi = 0; mi < 4; ++mi)
#pragma unroll
    for (int ni = 0; ni < 4; ++ni)
#pragma unroll
      for (int r4 = 0; r4 < 4; ++r4) {
        float v = acc[mi][ni][r4];
        int mg = m0 + wr * 64 + mi * 16 + g * 4 + r4;
        int ng = n0 + wc * 64 + ni * 16 + c;
        if (EPI == 0) {
          int which = ng >> 10, rem = ng & 1023;
          int hh = rem >> 6, dd = rem & 63;
          int bb = mg >> 11, tt = mg & 2047;
          size_t idx = (size_t)which * 8388608u + ((size_t)(bb * 16 + hh) * 2048 + tt) * 64 + dd;
          obf[idx] = f2bf(v);
        } else {
          of32[(size_t)mg * N + ng] = v;
        }
      }
}

// ---------------------------------------------------------------- flash attention (causal)
// q,k,v: [B*H, T, 64] bf16.  y out: [B, T, C] bf16.
__global__ __launch_bounds__(256, 2)
void attn_fwd(const unsigned short* __restrict__ qb,
              const unsigned short* __restrict__ kb,
              const unsigned short* __restrict__ vb,
              unsigned short* __restrict__ yb) {
  __shared__ unsigned short Kt[64 * 64];   // [kv row][d], rows XOR-swizzled at 16B
  __shared__ unsigned short Vt[64 * 64];   // transposed [d][kv], swizzled
  __shared__ unsigned short Pl[4 * 16 * 64]; // per-wave P, swizzled
  const int tid = threadIdx.x, w = tid >> 6, lane = tid & 63;
  const int c = lane & 15, g = lane >> 4;
  const int bh = blockIdx.x & 63;
  const int qt = 31 - (blockIdx.x >> 6);   // long blocks first
  const int q0 = qt * 64;
  const int b = bh >> 4, h = bh & 15;
  const size_t hb = (size_t)bh * 131072;   // 2048*64

  // Q fragments, held in registers for the whole block
  const unsigned short* qp = qb + hb + (size_t)(q0 + w * 16 + c) * 64;
  bf16x8 qf[2];
  qf[0] = *(const bf16x8*)(qp + g * 8);
  qf[1] = *(const bf16x8*)(qp + 32 + g * 8);

  f32x4 yacc[4];
#pragma unroll
  for (int i = 0; i < 4; ++i) yacc[i] = f32x4{0.f, 0.f, 0.f, 0.f};
  float mrun[4] = {-1e30f, -1e30f, -1e30f, -1e30f};
  float lsum[4] = {0.f, 0.f, 0.f, 0.f};
  unsigned short* pw = Pl + w * 1024;

  for (int kv = 0; kv <= qt; ++kv) {
    const int kv0 = kv * 64;
    if (kv) __syncthreads();
    // --- stage K (global_load_lds, source pre-swizzled so LDS holds swizzled rows)
#pragma unroll
    for (int r = 0; r < 2; ++r) {
      int chunk = w * 2 + r;
      int row = chunk * 8 + (lane >> 3);
      int bo = (lane & 7) * 16;
      int sbo = bo ^ ((row & 7) << 4);
      gll16((const char*)(kb + hb + (size_t)(kv0 + row) * 64) + sbo, Kt + chunk * 512);
    }
    // --- stage V transposed (reg-staged), swizzled writes (2 lanes/bank = free)
    {
      const unsigned short* vp = vb + hb + (size_t)(kv0 + lane) * 64 + w * 16;
      bf16x8 v0 = *(const bf16x8*)(vp);
      bf16x8 v1 = *(const bf16x8*)(vp + 8);
#pragma unroll
      for (int i = 0; i < 8; ++i) {
        int d0 = w * 16 + i;
        Vt[d0 * 64 + (lane ^ ((d0 & 7) << 3))] = (unsigned short)v0[i];
        int d1 = w * 16 + 8 + i;
        Vt[d1 * 64 + (lane ^ ((d1 & 7) << 3))] = (unsigned short)v1[i];
      }
    }
    __syncthreads();

    // --- S = Q @ K^T  (16x64 per wave)
    f32x4 sacc[4];
#pragma unroll
    for (int nt = 0; nt < 4; ++nt) sacc[nt] = f32x4{0.f, 0.f, 0.f, 0.f};
#pragma unroll
    for (int kk = 0; kk < 2; ++kk)
#pragma unroll
      for (int nt = 0; nt < 4; ++nt) {
        int row = nt * 16 + c;
        bf16x8 kf = *(const bf16x8*)(Kt + row * 64 + ((kk * 32 + g * 8) ^ ((row & 7) << 3)));
        sacc[nt] = MFMA16(qf[kk], kf, sacc[nt]);
      }

    // --- scale + causal mask + row max
    float mt[4];
#pragma unroll
    for (int r4 = 0; r4 < 4; ++r4) {
      int qrow = q0 + w * 16 + g * 4 + r4;
      float mx = -1e30f;
#pragma unroll
      for (int nt = 0; nt < 4; ++nt) {
        int col = kv0 + nt * 16 + c;
        float s = sacc[nt][r4] * 0.125f;
        s = (col <= qrow) ? s : -1e30f;
        sacc[nt][r4] = s;
        mx = fmaxf(mx, s);
      }
      mt[r4] = mx;
    }
#pragma unroll
    for (int off = 1; off < 16; off <<= 1)
#pragma unroll
      for (int r4 = 0; r4 < 4; ++r4) mt[r4] = fmaxf(mt[r4], __shfl_xor(mt[r4], off));

    // --- online softmax update; write P (bf16) to swizzled LDS
#pragma unroll
    for (int r4 = 0; r4 < 4; ++r4) {
      float mnew = fmaxf(mrun[r4], mt[r4]);
      float corr = __expf(mrun[r4] - mnew);
      mrun[r4] = mnew;
      float psum = 0.f;
      int prow = g * 4 + r4;
#pragma unroll
      for (int nt = 0; nt < 4; ++nt) {
        float p = __expf(sacc[nt][r4] - mnew);
        psum += p;
        pw[prow * 64 + ((nt * 16 + c) ^ ((prow & 7) << 3))] = f2bf(p);
      }
      lsum[r4] = lsum[r4] * corr + psum;
#pragma unroll
      for (int dt = 0; dt < 4; ++dt) yacc[dt][r4] *= corr;
    }

    // --- PV accumulate
#pragma unroll
    for (int kk = 0; kk < 2; ++kk) {
      bf16x8 pa = *(const bf16x8*)(pw + c * 64 + ((kk * 32 + g * 8) ^ ((c & 7) << 3)));
#pragma unroll
      for (int dt = 0; dt < 4; ++dt) {
        int n = dt * 16 + c;
        bf16x8 vf = *(const bf16x8*)(Vt + n * 64 + ((kk * 32 + g * 8) ^ ((n & 7) << 3)));
        yacc[dt] = MFMA16(pa, vf, yacc[dt]);
      }
    }
  }

  // --- epilogue: finish row sums, normalize, write y in [B,T,C]
#pragma unroll
  for (int off = 1; off < 16; off <<= 1)
#pragma unroll
    for (int r4 = 0; r4 < 4; ++r4) lsum[r4] += __shfl_xor(lsum[r4], off);
#pragma unroll
  for (int dt = 0; dt < 4; ++dt)
#pragma unroll
    for (int r4 = 0; r4 < 4; ++r4) {
      int row = q0 + w * 16 + g * 4 + r4;
      float yv = yacc[dt][r4] / lsum[r4];
      yb[((size_t)(b * 2048 + row)) * 1024 + h * 64 + dt * 16 + c] = f2bf(yv);
    }
}

// ---------------------------------------------------------------- launch
extern "C" void kernel_launch(void* const* d_in, const int* in_sizes, int n_in,
                              void* d_out, int out_size, void* d_ws, size_t ws_size,
                              hipStream_t stream) {
  const float* x     = (const float*)d_in[0];
  const float* wqkv  = (const float*)d_in[1];
  const float* wproj = (const float*)d_in[2];
  float* out = (float*)d_out;

  unsigned short* ws     = (unsigned short*)d_ws;
  unsigned short* xb     = ws;                       // 8388608
  unsigned short* wqkvb  = xb + 8388608;             // 3145728
  unsigned short* wprojb = wqkvb + 3145728;          // 1048576
  unsigned short* qkvb   = wprojb + 1048576;         // 3 * 8388608 (q,k,v)
  unsigned short* yb     = qkvb + 3 * 8388608;       // 8388608

  cvt_f32_bf16<<<8192, 256, 0, stream>>>(x, xb, 8388608);
  cvt_f32_bf16<<<3072, 256, 0, stream>>>(wqkv, wqkvb, 3145728);
  cvt_f32_bf16<<<1024, 256, 0, stream>>>(wproj, wprojb, 1048576);

  gemm_nt<0><<<dim3(64, 24), 256, 0, stream>>>(xb, wqkvb, qkvb, nullptr, 8192, 3072, 1024);
  attn_fwd<<<2048, 256, 0, stream>>>(qkvb, qkvb + 8388608, qkvb + 2 * 8388608, yb);
  gemm_nt<1><<<dim3(64, 8), 256, 0, stream>>>(yb, wprojb, nullptr, out, 8192, 1024, 1024);
}

// Round 2
// 180.431 us; speedup vs baseline: 1.1407x; 1.1407x over previous
//
#include <hip/hip_runtime.h>
#include <hip/hip_bf16.h>

typedef __attribute__((ext_vector_type(8))) short bf16x8;
typedef __attribute__((ext_vector_type(4))) float f32x4;
typedef __attribute__((ext_vector_type(4))) unsigned short ushort4v;
typedef __attribute__((ext_vector_type(2))) unsigned uint2v;

__device__ __forceinline__ unsigned short f2bf(float f) {
  union { float f; unsigned u; } v; v.f = f;
  unsigned r = v.u + 0x7FFFu + ((v.u >> 16) & 1u);
  return (unsigned short)(r >> 16);
}

__device__ __forceinline__ unsigned pack_bf2(float lo, float hi) {
  __hip_bfloat162 h = __float22bfloat162_rn(make_float2(lo, hi));
  union { __hip_bfloat162 h; unsigned u; } cv; cv.h = h; return cv.u;
}

__device__ __forceinline__ void gll16(const void* g, void* l) {
  __builtin_amdgcn_global_load_lds((const __attribute__((address_space(1))) void*)g,
                                   (__attribute__((address_space(3))) void*)l, 16, 0, 0);
}

#define MFMA16(a, b, c) __builtin_amdgcn_mfma_f32_16x16x32_bf16((a), (b), (c), 0, 0, 0)

// ---------------------------------------------------------------- convert
__global__ void cvt_f32_bf16(const float* __restrict__ s, unsigned short* __restrict__ d, int n) {
  int i = (blockIdx.x * blockDim.x + threadIdx.x) * 4;
  if (i >= n) return;
  float4 f = *(const float4*)(s + i);
  ushort4v r;
  r[0] = f2bf(f.x); r[1] = f2bf(f.y); r[2] = f2bf(f.z); r[3] = f2bf(f.w);
  *(ushort4v*)(d + i) = r;
}

// ---------------------------------------------------------------- GEMM NT (A[M][K] @ B[N][K]^T)
template<int EPI>
__global__ __launch_bounds__(256, 2)
void gemm_nt(const unsigned short* __restrict__ A,
             const unsigned short* __restrict__ B,
             unsigned short* __restrict__ obf,
             float* __restrict__ of32,
             int M, int N, int K) {
  __shared__ unsigned short At[128 * 64];
  __shared__ unsigned short Bt[128 * 64];
  const int tid = threadIdx.x, wid = tid >> 6, lane = tid & 63;
  const int c = lane & 15, g = lane >> 4;
  const int wr = wid >> 1, wc = wid & 1;
  const int m0 = blockIdx.x * 128, n0 = blockIdx.y * 128;

  f32x4 acc[4][4];
#pragma unroll
  for (int i = 0; i < 4; ++i)
#pragma unroll
    for (int j = 0; j < 4; ++j) acc[i][j] = f32x4{0.f, 0.f, 0.f, 0.f};

  for (int kt = 0; kt < K; kt += 64) {
    if (kt) __syncthreads();
#pragma unroll
    for (int r = 0; r < 4; ++r) {
      int chunk = wid * 4 + r;
      int row = chunk * 8 + (lane >> 3);
      int col = (lane & 7) * 8;
      gll16(A + (size_t)(m0 + row) * K + kt + col, At + chunk * 512);
      gll16(B + (size_t)(n0 + row) * K + kt + col, Bt + chunk * 512);
    }
    __syncthreads();
#pragma unroll
    for (int kk = 0; kk < 2; ++kk) {
      bf16x8 af[4], bfr[4];
#pragma unroll
      for (int i = 0; i < 4; ++i) {
        af[i]  = *(const bf16x8*)(At + (wr * 64 + i * 16 + c) * 64 + kk * 32 + g * 8);
        bfr[i] = *(const bf16x8*)(Bt + (wc * 64 + i * 16 + c) * 64 + kk * 32 + g * 8);
      }
#pragma unroll
      for (int mi = 0; mi < 4; ++mi)
#pragma unroll
        for (int ni = 0; ni < 4; ++ni)
          acc[mi][ni] = MFMA16(af[mi], bfr[ni], acc[mi][ni]);
    }
  }

#pragma unroll
  for (int mi = 0; mi < 4; ++mi)
#pragma unroll
    for (int ni = 0; ni < 4; ++ni)
#pragma unroll
      for (int r4 = 0; r4 < 4; ++r4) {
        float v = acc[mi][ni][r4];
        int mg = m0 + wr * 64 + mi * 16 + g * 4 + r4;
        int ng = n0 + wc * 64 + ni * 16 + c;
        if (EPI == 0) {
          int which = ng >> 10, rem = ng & 1023;
          int hh = rem >> 6, dd = rem & 63;
          int bb = mg >> 11, tt = mg & 2047;
          size_t idx = (size_t)which * 8388608u + ((size_t)(bb * 16 + hh) * 2048 + tt) * 64 + dd;
          obf[idx] = f2bf(v);
        } else {
          of32[(size_t)mg * N + ng] = v;
        }
      }
}

// ---------------------------------------------------------------- flash attention (causal, swapped-QK^T)
// q,k,v: [B*H, T, 64] bf16.  y out: [B, T, C] bf16.
__global__ __launch_bounds__(256, 4)
void attn_fwd(const unsigned short* __restrict__ qb,
              const unsigned short* __restrict__ kb,
              const unsigned short* __restrict__ vb,
              unsigned short* __restrict__ yb) {
  __shared__ unsigned short Kt[64 * 64];      // [kv][d], rows XOR-swizzled (16B granules)
  __shared__ unsigned short Vt[64 * 64];      // [d][kv] transposed, swizzled
  __shared__ unsigned short Pl[4 * 16 * 72];  // per wave: P [q=16][kv=64] rows padded to 72
  const int tid = threadIdx.x, w = tid >> 6, lane = tid & 63;
  const int c = lane & 15, g = lane >> 4;
  const int bh = blockIdx.x & 63;
  const int qt = 31 - (blockIdx.x >> 6);      // long blocks first
  const int q0 = qt * 64;
  const int b = bh >> 4, h = bh & 15;
  const size_t hb = (size_t)bh * 131072;      // 2048*64
  const float GAM = 0.125f * 1.44269504089f;  // scale folded into log2 domain

  // Q fragments (B-operand layout: lane holds Q[q=c][d=g*8..+7]) — register-resident
  const unsigned short* qp = qb + hb + (size_t)(q0 + w * 16 + c) * 64;
  bf16x8 qf0 = *(const bf16x8*)(qp + g * 8);
  bf16x8 qf1 = *(const bf16x8*)(qp + 32 + g * 8);

  f32x4 yacc[4];   // Y^T: lane holds q=c, d = dt*16 + g*4 + r
#pragma unroll
  for (int i = 0; i < 4; ++i) yacc[i] = f32x4{0.f, 0.f, 0.f, 0.f};
  float mrun = -1e30f, lsum = 0.f;
  unsigned short* pw = Pl + w * (16 * 72);

  for (int kv = 0; kv <= qt; ++kv) {
    const int kv0 = kv * 64;
    const bool diag = (kv == qt);
    if (kv) __syncthreads();
    // --- stage K via global_load_lds, source pre-swizzled
#pragma unroll
    for (int r = 0; r < 2; ++r) {
      int chunk = w * 2 + r;
      int row = chunk * 8 + (lane >> 3);
      int bo = (lane & 7) * 16;
      int sbo = bo ^ ((row & 7) << 4);
      gll16((const char*)(kb + hb + (size_t)(kv0 + row) * 64) + sbo, Kt + chunk * 512);
    }
    // --- stage V transposed: lane handles 2 kv rows, packed b32 swizzled writes
    {
      int kv2 = (lane & 31) * 2;
      int dblk = w * 16 + (lane >> 5) * 8;
      const unsigned short* vp = vb + hb + (size_t)(kv0 + kv2) * 64 + dblk;
      bf16x8 r0 = *(const bf16x8*)(vp);
      bf16x8 r1 = *(const bf16x8*)(vp + 64);
#pragma unroll
      for (int i = 0; i < 8; ++i) {
        int d = dblk + i;
        unsigned pk2 = ((unsigned)(unsigned short)r0[i]) | (((unsigned)(unsigned short)r1[i]) << 16);
        *(unsigned*)(Vt + d * 64 + (kv2 ^ ((d & 7) << 3))) = pk2;
      }
    }
    __syncthreads();

    // --- S^T = K @ Q^T : lane holds S^T[kv = nt*16 + g*4 + r][q = c]
    f32x4 sacc[4];
#pragma unroll
    for (int nt = 0; nt < 4; ++nt) sacc[nt] = f32x4{0.f, 0.f, 0.f, 0.f};
#pragma unroll
    for (int kk = 0; kk < 2; ++kk)
#pragma unroll
      for (int nt = 0; nt < 4; ++nt) {
        int row = nt * 16 + c;
        bf16x8 kf = *(const bf16x8*)(Kt + row * 64 + ((kk * 32 + g * 8) ^ ((row & 7) << 3)));
        sacc[nt] = MFMA16(kf, (kk ? qf1 : qf0), sacc[nt]);
      }

    // --- causal mask (diagonal tile only; uniform branch)
    if (diag) {
      int ql = w * 16 + c;
#pragma unroll
      for (int nt = 0; nt < 4; ++nt)
#pragma unroll
        for (int r = 0; r < 4; ++r)
          if (nt * 16 + g * 4 + r > ql) sacc[nt][r] = -1e30f;
    }

    // --- in-register row max (raw domain), then across g-lanes
    float m0 = -1e30f;
#pragma unroll
    for (int nt = 0; nt < 4; ++nt) {
      float a = fmaxf(fmaxf(sacc[nt][0], sacc[nt][1]), fmaxf(sacc[nt][2], sacc[nt][3]));
      m0 = fmaxf(m0, a);
    }
    m0 = fmaxf(m0, __shfl_xor(m0, 16));
    m0 = fmaxf(m0, __shfl_xor(m0, 32));

    // --- deferred rescale (T13): only when tile max exceeds running max + 32 (raw)
    if (__any(m0 > mrun + 32.0f)) {
      float mnew = fmaxf(mrun, m0);
      float corr = __builtin_amdgcn_exp2f(GAM * (mrun - mnew));
      lsum *= corr;
#pragma unroll
      for (int dt = 0; dt < 4; ++dt) yacc[dt] *= corr;
      mrun = mnew;
    }

    // --- P = exp2(GAM*s - GAM*mrun), packed b64 stores into per-wave P[q][kv]
    float bexp = -GAM * mrun;
    float psum = 0.f;
#pragma unroll
    for (int nt = 0; nt < 4; ++nt) {
      float p0 = __builtin_amdgcn_exp2f(fmaf(sacc[nt][0], GAM, bexp));
      float p1 = __builtin_amdgcn_exp2f(fmaf(sacc[nt][1], GAM, bexp));
      float p2 = __builtin_amdgcn_exp2f(fmaf(sacc[nt][2], GAM, bexp));
      float p3 = __builtin_amdgcn_exp2f(fmaf(sacc[nt][3], GAM, bexp));
      psum += (p0 + p1) + (p2 + p3);
      uint2v pkv;
      pkv[0] = pack_bf2(p0, p1);
      pkv[1] = pack_bf2(p2, p3);
      *(uint2v*)(pw + c * 72 + nt * 16 + g * 4) = pkv;
    }
    lsum += psum;

    // --- Y^T += V^T @ P^T
#pragma unroll
    for (int kk = 0; kk < 2; ++kk) {
      bf16x8 pb = *(const bf16x8*)(pw + c * 72 + kk * 32 + g * 8);
#pragma unroll
      for (int dt = 0; dt < 4; ++dt) {
        int n = dt * 16 + c;
        bf16x8 vf = *(const bf16x8*)(Vt + n * 64 + ((kk * 32 + g * 8) ^ ((n & 7) << 3)));
        yacc[dt] = MFMA16(vf, pb, yacc[dt]);
      }
    }
  }

  // --- epilogue: finish row sum across g-lanes, normalize, vectorized y store
  lsum += __shfl_xor(lsum, 16);
  lsum += __shfl_xor(lsum, 32);
  float inv = 1.0f / lsum;
  int row = q0 + w * 16 + c;
  unsigned short* yp = yb + ((size_t)(b * 2048 + row)) * 1024 + h * 64;
#pragma unroll
  for (int dt = 0; dt < 4; ++dt) {
    uint2v pkv;
    pkv[0] = pack_bf2(yacc[dt][0] * inv, yacc[dt][1] * inv);
    pkv[1] = pack_bf2(yacc[dt][2] * inv, yacc[dt][3] * inv);
    *(uint2v*)(yp + dt * 16 + g * 4) = pkv;
  }
}

// ---------------------------------------------------------------- launch
extern "C" void kernel_launch(void* const* d_in, const int* in_sizes, int n_in,
                              void* d_out, int out_size, void* d_ws, size_t ws_size,
                              hipStream_t stream) {
  const float* x     = (const float*)d_in[0];
  const float* wqkv  = (const float*)d_in[1];
  const float* wproj = (const float*)d_in[2];
  float* out = (float*)d_out;

  unsigned short* ws     = (unsigned short*)d_ws;
  unsigned short* xb     = ws;                       // 8388608
  unsigned short* wqkvb  = xb + 8388608;             // 3145728
  unsigned short* wprojb = wqkvb + 3145728;          // 1048576
  unsigned short* qkvb   = wprojb + 1048576;         // 3 * 8388608 (q,k,v)
  unsigned short* yb     = qkvb + 3 * 8388608;       // 8388608

  cvt_f32_bf16<<<8192, 256, 0, stream>>>(x, xb, 8388608);
  cvt_f32_bf16<<<3072, 256, 0, stream>>>(wqkv, wqkvb, 3145728);
  cvt_f32_bf16<<<1024, 256, 0, stream>>>(wproj, wprojb, 1048576);

  gemm_nt<0><<<dim3(64, 24), 256, 0, stream>>>(xb, wqkvb, qkvb, nullptr, 8192, 3072, 1024);
  attn_fwd<<<2048, 256, 0, stream>>>(qkvb, qkvb + 8388608, qkvb + 2 * 8388608, yb);
  gemm_nt<1><<<dim3(64, 8), 256, 0, stream>>>(yb, wprojb, nullptr, out, 8192, 1024, 1024);
}

// Round 4
// 175.275 us; speedup vs baseline: 1.1742x; 1.0294x over previous
//
#include <hip/hip_runtime.h>
#include <hip/hip_bf16.h>

typedef __attribute__((ext_vector_type(8))) short bf16x8;
typedef __attribute__((ext_vector_type(4))) float f32x4;
typedef __attribute__((ext_vector_type(4))) unsigned short ushort4v;
typedef __attribute__((ext_vector_type(2))) unsigned uint2v;

__device__ __forceinline__ unsigned short f2bf(float f) {
  union { float f; unsigned u; } v; v.f = f;
  unsigned r = v.u + 0x7FFFu + ((v.u >> 16) & 1u);
  return (unsigned short)(r >> 16);
}

__device__ __forceinline__ unsigned pack_bf2(float lo, float hi) {
  __hip_bfloat162 h = __float22bfloat162_rn(make_float2(lo, hi));
  union { __hip_bfloat162 h; unsigned u; } cv; cv.h = h; return cv.u;
}

__device__ __forceinline__ void gll16(const void* g, void* l) {
  __builtin_amdgcn_global_load_lds((const __attribute__((address_space(1))) void*)g,
                                   (__attribute__((address_space(3))) void*)l, 16, 0, 0);
}

#define MFMA16(a, b, c) __builtin_amdgcn_mfma_f32_16x16x32_bf16((a), (b), (c), 0, 0, 0)

// ---------------------------------------------------------------- convert
__global__ void cvt_f32_bf16(const float* __restrict__ s, unsigned short* __restrict__ d, int n) {
  int i = (blockIdx.x * blockDim.x + threadIdx.x) * 4;
  if (i >= n) return;
  float4 f = *(const float4*)(s + i);
  ushort4v r;
  r[0] = f2bf(f.x); r[1] = f2bf(f.y); r[2] = f2bf(f.z); r[3] = f2bf(f.w);
  *(ushort4v*)(d + i) = r;
}

// ---------------------------------------------------------------- GEMM NT, 8-phase schedule
// BM=256, BN=128, BK=64, 8 waves (4M x 2N), per-wave 64x64 output.
// LDS element offsets: Ab(par) = par*16384 ; Bb(par) = 32768 + par*8192  (96 KiB total)
template<int EPI>
__global__ __launch_bounds__(512, 1)
void gemm8(const unsigned short* __restrict__ A,
           const unsigned short* __restrict__ B,
           unsigned short* __restrict__ obf,
           float* __restrict__ of32,
           int M, int N, int K) {
  extern __shared__ unsigned short lds[];
  const int tid = threadIdx.x, wid = tid >> 6, lane = tid & 63;
  const int c = lane & 15, g = lane >> 4;
  const int wr = wid >> 1, wc = wid & 1;
  const int nbn = N >> 7;
  const int nwg = gridDim.x;
  int wg = (blockIdx.x & 7) * (nwg >> 3) + (blockIdx.x >> 3);  // XCD swizzle (nwg%8==0)
  const int m0 = (wg / nbn) * 256, n0 = (wg % nbn) * 128;
  const int NT = K >> 6;
  const size_t rb = (size_t)K * 2;   // global row bytes
  const int swz = (c & 7) << 4;      // ds_read XOR key (16B granules)

  // per-lane pre-swizzled global source (m173): lane stages LDS (row8=l>>3, col16=l&7),
  // reads global col16 = (l&7)^row8
  const int r8 = lane >> 3;
  const char* Ag = (const char*)A + (size_t)m0 * rb + (size_t)r8 * rb + (size_t)(((lane & 7) ^ r8) * 16);
  const char* Bg = (const char*)B + (size_t)n0 * rb + (size_t)r8 * rb + (size_t)(((lane & 7) ^ r8) * 16);

  auto stageA = [&](int t, int par) {   // 32 chunks of 8 rows; wave does 4
#pragma unroll
    for (int j = 0; j < 4; ++j) {
      int ch = wid * 4 + j;
      gll16(Ag + (size_t)(ch * 8) * rb + t * 128, lds + par * 16384 + ch * 512);
    }
  };
  auto stageB = [&](int t, int par) {   // 16 chunks; wave does 2
#pragma unroll
    for (int j = 0; j < 2; ++j) {
      int ch = wid * 2 + j;
      gll16(Bg + (size_t)(ch * 8) * rb + t * 128, lds + 32768 + par * 8192 + ch * 512);
    }
  };

  f32x4 acc[4][4];
#pragma unroll
  for (int i = 0; i < 4; ++i)
#pragma unroll
    for (int j = 0; j < 4; ++j) acc[i][j] = f32x4{0.f, 0.f, 0.f, 0.f};

  // prologue: A(0),B(0) -> buf0 ; A(1) -> buf1 ; wait until only A(1) (4 loads) in flight
  stageA(0, 0); stageB(0, 0); stageA(1, 1);
  asm volatile("s_waitcnt vmcnt(4)" ::: "memory");
  __builtin_amdgcn_s_barrier();

  for (int t = 0; t < NT; ++t) {
    const int cur = t & 1;
    const unsigned short* Ac = lds + cur * 16384;
    const unsigned short* Bc = lds + 32768 + cur * 8192;
    // ---- phase 0: read A(all)+B(n0-1); stage B(t+1); MFMA (m0-3 x n0-1)
    bf16x8 af[4][2], bf0[2][2];
#pragma unroll
    for (int mi = 0; mi < 4; ++mi) {
      int arow = wr * 64 + mi * 16 + c;
#pragma unroll
      for (int kk = 0; kk < 2; ++kk)
        af[mi][kk] = *(const bf16x8*)((const char*)Ac + arow * 128 + ((kk * 64 + g * 16) ^ swz));
    }
#pragma unroll
    for (int ni = 0; ni < 2; ++ni) {
      int brow = wc * 64 + ni * 16 + c;
#pragma unroll
      for (int kk = 0; kk < 2; ++kk)
        bf0[ni][kk] = *(const bf16x8*)((const char*)Bc + brow * 128 + ((kk * 64 + g * 16) ^ swz));
    }
    if (t + 1 < NT) stageB(t + 1, cur ^ 1);
    __builtin_amdgcn_s_barrier();
    asm volatile("s_waitcnt lgkmcnt(0)" ::: "memory");
    __builtin_amdgcn_sched_barrier(0);
    __builtin_amdgcn_s_setprio(1);
#pragma unroll
    for (int kk = 0; kk < 2; ++kk)
#pragma unroll
      for (int mi = 0; mi < 4; ++mi)
#pragma unroll
        for (int ni = 0; ni < 2; ++ni)
          acc[mi][ni] = MFMA16(af[mi][kk], bf0[ni][kk], acc[mi][ni]);
    __builtin_amdgcn_s_setprio(0);
    __builtin_amdgcn_s_barrier();
    // ---- phase 1: read B(n2-3); stage A(t+2); MFMA (m0-3 x n2-3); vmcnt(4)
    bf16x8 bf1[2][2];
#pragma unroll
    for (int ni = 0; ni < 2; ++ni) {
      int brow = wc * 64 + (ni + 2) * 16 + c;
#pragma unroll
      for (int kk = 0; kk < 2; ++kk)
        bf1[ni][kk] = *(const bf16x8*)((const char*)Bc + brow * 128 + ((kk * 64 + g * 16) ^ swz));
    }
    if (t + 2 < NT) stageA(t + 2, cur);
    __builtin_amdgcn_s_barrier();
    asm volatile("s_waitcnt lgkmcnt(0)" ::: "memory");
    __builtin_amdgcn_sched_barrier(0);
    __builtin_amdgcn_s_setprio(1);
#pragma unroll
    for (int kk = 0; kk < 2; ++kk)
#pragma unroll
      for (int mi = 0; mi < 4; ++mi)
#pragma unroll
        for (int ni = 0; ni < 2; ++ni)
          acc[mi][ni + 2] = MFMA16(af[mi][kk], bf1[ni][kk], acc[mi][ni + 2]);
    __builtin_amdgcn_s_setprio(0);
    asm volatile("s_waitcnt vmcnt(4)" ::: "memory");
    __builtin_amdgcn_s_barrier();
  }

  // ---- epilogue
#pragma unroll
  for (int mi = 0; mi < 4; ++mi)
#pragma unroll
    for (int ni = 0; ni < 4; ++ni)
#pragma unroll
      for (int r4 = 0; r4 < 4; ++r4) {
        float v = acc[mi][ni][r4];
        int mg = m0 + wr * 64 + mi * 16 + g * 4 + r4;
        int ng = n0 + wc * 64 + ni * 16 + c;
        if (EPI == 0) {
          int which = ng >> 10, rem = ng & 1023;
          int hh = rem >> 6, dd = rem & 63;
          int bb = mg >> 11, tt = mg & 2047;
          size_t idx = (size_t)which * 8388608u + ((size_t)(bb * 16 + hh) * 2048 + tt) * 64 + dd;
          obf[idx] = f2bf(v);
        } else {
          of32[(size_t)mg * N + ng] = v;
        }
      }
}

// ---------------------------------------------------------------- flash attention (causal, swapped-QK^T)
__global__ __launch_bounds__(256, 4)
void attn_fwd(const unsigned short* __restrict__ qb,
              const unsigned short* __restrict__ kb,
              const unsigned short* __restrict__ vb,
              unsigned short* __restrict__ yb) {
  __shared__ unsigned short Kt[64 * 64];
  __shared__ unsigned short Vt[64 * 64];
  __shared__ unsigned short Pl[4 * 16 * 72];
  const int tid = threadIdx.x, w = tid >> 6, lane = tid & 63;
  const int c = lane & 15, g = lane >> 4;
  const int bh = blockIdx.x & 63;
  const int qt = 31 - (blockIdx.x >> 6);
  const int q0 = qt * 64;
  const int b = bh >> 4, h = bh & 15;
  const size_t hb = (size_t)bh * 131072;
  const float GAM = 0.125f * 1.44269504089f;

  const unsigned short* qp = qb + hb + (size_t)(q0 + w * 16 + c) * 64;
  bf16x8 qf0 = *(const bf16x8*)(qp + g * 8);
  bf16x8 qf1 = *(const bf16x8*)(qp + 32 + g * 8);

  f32x4 yacc[4];
#pragma unroll
  for (int i = 0; i < 4; ++i) yacc[i] = f32x4{0.f, 0.f, 0.f, 0.f};
  float mrun = -1e30f, lsum = 0.f;
  unsigned short* pw = Pl + w * (16 * 72);

  for (int kv = 0; kv <= qt; ++kv) {
    const int kv0 = kv * 64;
    const bool diag = (kv == qt);
    if (kv) __syncthreads();
#pragma unroll
    for (int r = 0; r < 2; ++r) {
      int chunk = w * 2 + r;
      int row = chunk * 8 + (lane >> 3);
      int bo = (lane & 7) * 16;
      int sbo = bo ^ ((row & 7) << 4);
      gll16((const char*)(kb + hb + (size_t)(kv0 + row) * 64) + sbo, Kt + chunk * 512);
    }
    {
      int kv2 = (lane & 31) * 2;
      int dblk = w * 16 + (lane >> 5) * 8;
      const unsigned short* vp = vb + hb + (size_t)(kv0 + kv2) * 64 + dblk;
      bf16x8 r0 = *(const bf16x8*)(vp);
      bf16x8 r1 = *(const bf16x8*)(vp + 64);
#pragma unroll
      for (int i = 0; i < 8; ++i) {
        int d = dblk + i;
        unsigned pk2 = ((unsigned)(unsigned short)r0[i]) | (((unsigned)(unsigned short)r1[i]) << 16);
        *(unsigned*)(Vt + d * 64 + (kv2 ^ ((d & 7) << 3))) = pk2;
      }
    }
    __syncthreads();

    f32x4 sacc[4];
#pragma unroll
    for (int nt = 0; nt < 4; ++nt) sacc[nt] = f32x4{0.f, 0.f, 0.f, 0.f};
#pragma unroll
    for (int kk = 0; kk < 2; ++kk)
#pragma unroll
      for (int nt = 0; nt < 4; ++nt) {
        int row = nt * 16 + c;
        bf16x8 kf = *(const bf16x8*)(Kt + row * 64 + ((kk * 32 + g * 8) ^ ((row & 7) << 3)));
        sacc[nt] = MFMA16(kf, (kk ? qf1 : qf0), sacc[nt]);
      }

    if (diag) {
      int ql = w * 16 + c;
#pragma unroll
      for (int nt = 0; nt < 4; ++nt)
#pragma unroll
        for (int r = 0; r < 4; ++r)
          if (nt * 16 + g * 4 + r > ql) sacc[nt][r] = -1e30f;
    }

    float m0 = -1e30f;
#pragma unroll
    for (int nt = 0; nt < 4; ++nt) {
      float a = fmaxf(fmaxf(sacc[nt][0], sacc[nt][1]), fmaxf(sacc[nt][2], sacc[nt][3]));
      m0 = fmaxf(m0, a);
    }
    m0 = fmaxf(m0, __shfl_xor(m0, 16));
    m0 = fmaxf(m0, __shfl_xor(m0, 32));

    if (__any(m0 > mrun + 32.0f)) {
      float mnew = fmaxf(mrun, m0);
      float corr = __builtin_amdgcn_exp2f(GAM * (mrun - mnew));
      lsum *= corr;
#pragma unroll
      for (int dt = 0; dt < 4; ++dt) yacc[dt] *= corr;
      mrun = mnew;
    }

    float bexp = -GAM * mrun;
    float psum = 0.f;
#pragma unroll
    for (int nt = 0; nt < 4; ++nt) {
      float p0 = __builtin_amdgcn_exp2f(fmaf(sacc[nt][0], GAM, bexp));
      float p1 = __builtin_amdgcn_exp2f(fmaf(sacc[nt][1], GAM, bexp));
      float p2 = __builtin_amdgcn_exp2f(fmaf(sacc[nt][2], GAM, bexp));
      float p3 = __builtin_amdgcn_exp2f(fmaf(sacc[nt][3], GAM, bexp));
      psum += (p0 + p1) + (p2 + p3);
      uint2v pkv;
      pkv[0] = pack_bf2(p0, p1);
      pkv[1] = pack_bf2(p2, p3);
      *(uint2v*)(pw + c * 72 + nt * 16 + g * 4) = pkv;
    }
    lsum += psum;

#pragma unroll
    for (int kk = 0; kk < 2; ++kk) {
      bf16x8 pb = *(const bf16x8*)(pw + c * 72 + kk * 32 + g * 8);
#pragma unroll
      for (int dt = 0; dt < 4; ++dt) {
        int n = dt * 16 + c;
        bf16x8 vf = *(const bf16x8*)(Vt + n * 64 + ((kk * 32 + g * 8) ^ ((n & 7) << 3)));
        yacc[dt] = MFMA16(vf, pb, yacc[dt]);
      }
    }
  }

  lsum += __shfl_xor(lsum, 16);
  lsum += __shfl_xor(lsum, 32);
  float inv = 1.0f / lsum;
  int row = q0 + w * 16 + c;
  unsigned short* yp = yb + ((size_t)(b * 2048 + row)) * 1024 + h * 64;
#pragma unroll
  for (int dt = 0; dt < 4; ++dt) {
    uint2v pkv;
    pkv[0] = pack_bf2(yacc[dt][0] * inv, yacc[dt][1] * inv);
    pkv[1] = pack_bf2(yacc[dt][2] * inv, yacc[dt][3] * inv);
    *(uint2v*)(yp + dt * 16 + g * 4) = pkv;
  }
}

// ---------------------------------------------------------------- launch
extern "C" void kernel_launch(void* const* d_in, const int* in_sizes, int n_in,
                              void* d_out, int out_size, void* d_ws, size_t ws_size,
                              hipStream_t stream) {
  const float* x     = (const float*)d_in[0];
  const float* wqkv  = (const float*)d_in[1];
  const float* wproj = (const float*)d_in[2];
  float* out = (float*)d_out;

  unsigned short* ws     = (unsigned short*)d_ws;
  unsigned short* xb     = ws;                       // 8388608
  unsigned short* wqkvb  = xb + 8388608;             // 3145728
  unsigned short* wprojb = wqkvb + 3145728;          // 1048576
  unsigned short* qkvb   = wprojb + 1048576;         // 3 * 8388608 (q,k,v)
  unsigned short* yb     = qkvb + 3 * 8388608;       // 8388608

  cvt_f32_bf16<<<8192, 256, 0, stream>>>(x, xb, 8388608);
  cvt_f32_bf16<<<3072, 256, 0, stream>>>(wqkv, wqkvb, 3145728);
  cvt_f32_bf16<<<1024, 256, 0, stream>>>(wproj, wprojb, 1048576);

  // LDS: A 2x256x64 + B 2x128x64 bf16 = 96 KiB
  gemm8<0><<<768, 512, 98304, stream>>>(xb, wqkvb, qkvb, nullptr, 8192, 3072, 1024);
  attn_fwd<<<2048, 256, 0, stream>>>(qkvb, qkvb + 8388608, qkvb + 2 * 8388608, yb);
  gemm8<1><<<256, 512, 98304, stream>>>(yb, wprojb, nullptr, out, 8192, 1024, 1024);
}